// Round 4
// baseline (1735.933 us; speedup 1.0000x reference)
//
#include <hip/hip_runtime.h>
#include <stdint.h>

typedef unsigned int u32;
typedef unsigned long long u64;
typedef _Float16 half8 __attribute__((ext_vector_type(8)));
typedef _Float16 half4 __attribute__((ext_vector_type(4)));
typedef float f32x4 __attribute__((ext_vector_type(4)));

#define M_TOT 32768
#define D_DIM 256
#define N_E   8192
#define BM 64
#define BN 256
#define SA 264   // As row stride (halfs)
#define SB 40    // Bs row stride (halfs)
// flag margin in RAW f16-acc units (= 4e-5 score units / c2, c2 = 2/8192):
// covers 2*(ulp(256)/2)=3.05e-5 quantization + 3.5-sigma f16 noise + slack
#define MARGIN_RAW 0.16384f

__device__ __forceinline__ u32 umax32(u32 a, u32 b) { return a > b ? a : b; }
__device__ __forceinline__ u32 umin32(u32 a, u32 b) { return a < b ? a : b; }
__device__ __forceinline__ u64 umax64(u64 a, u64 b) { return a > b ? a : b; }
__device__ __forceinline__ u64 umin64(u64 a, u64 b) { return a < b ? a : b; }

__device__ __forceinline__ u32 map_f32(float f) {
    u32 u = __float_as_uint(f);
    return u ^ ((u32)((int)u >> 31) | 0x80000000u);
}
__device__ __forceinline__ float unmap_f32(u32 u) {
    return __uint_as_float(u ^ ((u & 0x80000000u) ? 0x80000000u : 0xFFFFFFFFu));
}

// ---------------- init ------------------------------------------------------
__global__ void k_init(int* counts, int* amb_cnt, double* accum, u64* bg) {
    int i = blockIdx.x * 256 + threadIdx.x;
    if (i < M_TOT) bg[i] = ~0ull;
    if (i < N_E) counts[i] = 0;
    if (i == 0) { *amb_cnt = 0; *accum = 0.0; }
}

// ---------------- emb -> f16 scaled x8192 (exact pow2) ----------------------
__global__ void k_prep_emb(const float* __restrict__ emb, _Float16* __restrict__ emb_h) {
    long i = (long)blockIdx.x * 1024 + threadIdx.x * 4;
    float4 v = *(const float4*)(emb + i);
    half4 h = { (_Float16)(v.x * 8192.0f), (_Float16)(v.y * 8192.0f),
                (_Float16)(v.z * 8192.0f), (_Float16)(v.w * 8192.0f) };
    *(half4*)(emb_h + i) = h;
}

// ---------------- z -> f16 --------------------------------------------------
__global__ void k_prep_z(const float* __restrict__ z, _Float16* __restrict__ z_h) {
    long i = (long)blockIdx.x * 1024 + threadIdx.x * 4;
    float4 v = *(const float4*)(z + i);
    half4 h = { (_Float16)v.x, (_Float16)v.y, (_Float16)v.z, (_Float16)v.w };
    *(half4*)(z_h + i) = h;
}

// ---------------- f16 MFMA screen: argmax(dot) + top-2 gap flag -------------
__global__ __launch_bounds__(256, 2) void k_argmax(
    const _Float16* __restrict__ z_h, const _Float16* __restrict__ emb_h,
    float* __restrict__ out_idx_f, int* __restrict__ idx_int,
    int* __restrict__ amb_list, int* __restrict__ amb_cnt)
{
    __shared__ _Float16 As[BM * SA];
    __shared__ _Float16 Bs[BN * SB];
    __shared__ u64 redB1[4][BM];
    __shared__ u32 redB2[4][BM];

    const int t = threadIdx.x;
    const int w = t >> 6;
    const int lane = t & 63;
    const int quad = lane >> 4;
    const int l15 = lane & 15;
    const int m0 = blockIdx.x * BM;
    const int wn = w * 64;

    #pragma unroll
    for (int i = 0; i < 8; ++i) {
        int c = i * 256 + t;
        int row = c >> 5, seg = c & 31;
        *(half8*)&As[row * SA + seg * 8] = *(const half8*)&z_h[(long)(m0 + row) * D_DIM + seg * 8];
    }

    f32x4 acc[4][4];
    u64 B1[16];
    u32 B2[16];
    #pragma unroll
    for (int g = 0; g < 16; ++g) { B1[g] = 0ull; B2[g] = 0u; }

    for (int nt = 0; nt < N_E / BN; ++nt) {
        const int n0 = nt * BN;
        #pragma unroll
        for (int mi = 0; mi < 4; ++mi)
            #pragma unroll
            for (int ni = 0; ni < 4; ++ni)
                acc[mi][ni] = (f32x4){0.f, 0.f, 0.f, 0.f};

        for (int ks = 0; ks < 8; ++ks) {
            __syncthreads();
            #pragma unroll
            for (int i = 0; i < 4; ++i) {
                int c = i * 256 + t;
                int col = c >> 2, seg = c & 3;
                *(half8*)&Bs[col * SB + seg * 8] =
                    *(const half8*)&emb_h[(long)(n0 + col) * D_DIM + ks * 32 + seg * 8];
            }
            __syncthreads();
            half8 af[4], bf[4];
            #pragma unroll
            for (int mi = 0; mi < 4; ++mi)
                af[mi] = *(const half8*)&As[(mi * 16 + l15) * SA + ks * 32 + quad * 8];
            #pragma unroll
            for (int ni = 0; ni < 4; ++ni)
                bf[ni] = *(const half8*)&Bs[(wn + ni * 16 + l15) * SB + quad * 8];
            #pragma unroll
            for (int mi = 0; mi < 4; ++mi)
                #pragma unroll
                for (int ni = 0; ni < 4; ++ni)
                    acc[mi][ni] = __builtin_amdgcn_mfma_f32_16x16x32_f16(af[mi], bf[ni], acc[mi][ni], 0, 0, 0);
        }

        // C/D: col(n)=lane&15, row(m)=quad*4+reg
        u32 idxw[4];
        #pragma unroll
        for (int ni = 0; ni < 4; ++ni)
            idxw[ni] = (u32)(N_E - 1 - (n0 + wn + ni * 16 + l15));
        #pragma unroll
        for (int mi = 0; mi < 4; ++mi) {
            #pragma unroll
            for (int reg = 0; reg < 4; ++reg) {
                u32 s[4]; u64 p[4];
                #pragma unroll
                for (int ni = 0; ni < 4; ++ni) {
                    s[ni] = map_f32(acc[mi][ni][reg]);   // raw f16-dot score
                    p[ni] = ((u64)s[ni] << 32) | (u64)idxw[ni];
                }
                u64 t1 = umax64(umax64(p[0], p[1]), umax64(p[2], p[3]));
                u32 a = umax32(s[0], s[1]), b = umin32(s[0], s[1]);
                u32 c = umax32(s[2], s[3]), d = umin32(s[2], s[3]);
                u32 t2 = umax32(umin32(a, c), umax32(b, d));
                int g = mi * 4 + reg;
                u32 b1s = (u32)(B1[g] >> 32), t1s = (u32)(t1 >> 32);
                B2[g] = umax32(umax32(B2[g], t2), umin32(b1s, t1s));
                B1[g] = umax64(B1[g], t1);
            }
        }
    }

    #pragma unroll
    for (int g = 0; g < 16; ++g) {
        u64 b1 = B1[g]; u32 b2 = B2[g];
        for (int o = 1; o < 16; o <<= 1) {
            u64 ob1 = __shfl_xor(b1, o, 64);
            u32 ob2 = __shfl_xor(b2, o, 64);
            u32 s1 = (u32)(b1 >> 32), so = (u32)(ob1 >> 32);
            b2 = umax32(umax32(b2, ob2), umin32(s1, so));
            b1 = umax64(b1, ob1);
        }
        B1[g] = b1; B2[g] = b2;
    }
    if (l15 == 0) {
        #pragma unroll
        for (int g = 0; g < 16; ++g) {
            int mi = g >> 2, reg = g & 3;
            int r = mi * 16 + quad * 4 + reg;
            redB1[w][r] = B1[g];
            redB2[w][r] = B2[g];
        }
    }
    __syncthreads();
    if (t < BM) {
        u64 b1 = 0ull; u32 b2 = 0u;
        #pragma unroll
        for (int ww = 0; ww < 4; ++ww) {
            u64 v1 = redB1[ww][t]; u32 v2 = redB2[ww][t];
            u32 s1 = (u32)(b1 >> 32), so = (u32)(v1 >> 32);
            b2 = umax32(umax32(b2, v2), umin32(s1, so));
            b1 = umax64(b1, v1);
        }
        int idx = (int)(N_E - 1 - (u32)(b1 & 0xFFFFFFFFu));
        int m = m0 + t;
        out_idx_f[m] = (float)idx;
        idx_int[m] = idx;
        float gap = unmap_f32((u32)(b1 >> 32)) - unmap_f32(b2);
        if (gap < MARGIN_RAW) {
            int p = atomicAdd(amb_cnt, 1);
            if (p < M_TOT) amb_list[p] = m;
        }
    }
}

// ---------------- bitwise np-fp32 emulation for flagged rows ----------------
// q[n] = fl(z2_np - 2*dot_np[n]); dot = numpy einsum baseline-SSE npyv loop:
// 4 lanes, 16-elem iters, muladd chain i=3..0 (unfused), hsum (s0+s1)+(s2+s3).
// (+e2 provably rounds away: e2 ~ 3.8e-6 < ulp(q)/2.)
__global__ __launch_bounds__(256) void k_emu(
    const float* __restrict__ z, const float* __restrict__ emb,
    const int* __restrict__ amb_list, const int* __restrict__ amb_cnt,
    u64* __restrict__ bg)
{
    #pragma clang fp contract(off)
    __shared__ __align__(16) float zt[64 * D_DIM];   // 64 KB
    __shared__ int ml[64];
    __shared__ float z2s[64];
    int cnt = *amb_cnt; if (cnt > M_TOT) cnt = M_TOT;
    const int t = threadIdx.x;
    const int my = t >> 4, nx = t & 15;
    const int ngroups = (cnt + 63) >> 6;
    const int nunits = ngroups * 32;   // 32 slices x 256 cols

    for (int u = blockIdx.x; u < nunits; u += gridDim.x) {
        const int g = u >> 5, slice = u & 31;
        __syncthreads();
        if (t < 64) { int gi = g * 64 + t; ml[t] = amb_list[gi < cnt ? gi : cnt - 1]; }
        __syncthreads();
        for (int i = 0; i < 16; ++i) {          // 64 rows x 64 float4 = 4096
            int c = i * 256 + t;
            int row = c >> 6, w4 = c & 63;
            *(float4*)&zt[row * D_DIM + w4 * 4] =
                *(const float4*)&z[(long)ml[row] * D_DIM + w4 * 4];
        }
        __syncthreads();
        if (t < 64) {   // z2: numpy pairwise (128+128, 8 accumulators)
            const float* x = &zt[t * D_DIM];
            float tot = 0.0f;
            for (int h = 0; h < 2; ++h) {
                const float* p = x + h * 128;
                float r0 = p[0]*p[0], r1 = p[1]*p[1], r2 = p[2]*p[2], r3 = p[3]*p[3];
                float r4 = p[4]*p[4], r5 = p[5]*p[5], r6 = p[6]*p[6], r7 = p[7]*p[7];
                for (int i = 8; i < 128; i += 8) {
                    r0 += p[i+0]*p[i+0]; r1 += p[i+1]*p[i+1];
                    r2 += p[i+2]*p[i+2]; r3 += p[i+3]*p[i+3];
                    r4 += p[i+4]*p[i+4]; r5 += p[i+5]*p[i+5];
                    r6 += p[i+6]*p[i+6]; r7 += p[i+7]*p[i+7];
                }
                tot = tot + (((r0 + r1) + (r2 + r3)) + ((r4 + r5) + (r6 + r7)));
            }
            z2s[t] = tot;
        }
        __syncthreads();

        for (int r = 0; r < 4; ++r) {
            const int row = my * 4 + r;
            const float* zr = &zt[row * D_DIM];
            const float z2v = z2s[row];
            u64 best = ~0ull;
            for (int cb = 0; cb < 4; ++cb) {
                const int nb = (slice * 4 + cb) * 64 + nx * 4;
                const float* e0p = emb + (long)nb * D_DIM;
                float va[4][4];
                #pragma unroll
                for (int j = 0; j < 4; ++j)
                    #pragma unroll
                    for (int l = 0; l < 4; ++l) va[j][l] = 0.0f;
                for (int it = 0; it < 16; ++it) {
                    float4 zc0 = *(const float4*)(zr + it * 16);
                    float4 zc1 = *(const float4*)(zr + it * 16 + 4);
                    float4 zc2 = *(const float4*)(zr + it * 16 + 8);
                    float4 zc3 = *(const float4*)(zr + it * 16 + 12);
                    #pragma unroll
                    for (int j = 0; j < 4; ++j) {
                        const float* ep = e0p + j * D_DIM + it * 16;
                        float4 e0 = *(const float4*)(ep);
                        float4 e1 = *(const float4*)(ep + 4);
                        float4 e2v = *(const float4*)(ep + 8);
                        float4 e3 = *(const float4*)(ep + 12);
                        va[j][0] = zc0.x*e0.x + (zc1.x*e1.x + (zc2.x*e2v.x + (zc3.x*e3.x + va[j][0])));
                        va[j][1] = zc0.y*e0.y + (zc1.y*e1.y + (zc2.y*e2v.y + (zc3.y*e3.y + va[j][1])));
                        va[j][2] = zc0.z*e0.z + (zc1.z*e1.z + (zc2.z*e2v.z + (zc3.z*e3.z + va[j][2])));
                        va[j][3] = zc0.w*e0.w + (zc1.w*e1.w + (zc2.w*e2v.w + (zc3.w*e3.w + va[j][3])));
                    }
                }
                #pragma unroll
                for (int j = 0; j < 4; ++j) {
                    float dot = (va[j][0] + va[j][1]) + (va[j][2] + va[j][3]);
                    float q = z2v - 2.0f * dot;
                    best = umin64(best, ((u64)map_f32(q) << 32) | (u64)(nb + j));
                }
            }
            for (int o = 1; o < 16; o <<= 1) best = umin64(best, __shfl_xor(best, o, 64));
            if (nx == 0) atomicMin(&bg[ml[row]], best);
        }
    }
}

// ---------------- write back emulated winners -------------------------------
__global__ void k_emu_write(const int* __restrict__ amb_list, const int* __restrict__ amb_cnt,
                            const u64* __restrict__ bg,
                            float* __restrict__ out_idx_f, int* __restrict__ idx_int)
{
    int cnt = *amb_cnt; if (cnt > M_TOT) cnt = M_TOT;
    for (int i = blockIdx.x * 256 + threadIdx.x; i < cnt; i += gridDim.x * 256) {
        int m = amb_list[i];
        u64 b = bg[m];
        if (b != ~0ull) {
            int n = (int)(b & 0xFFFFFFFFu);
            out_idx_f[m] = (float)n;
            idx_int[m] = n;
        }
    }
}

// ---------------- z_q gather + sum(diff^2) + histogram ----------------------
__global__ void k_out(const float* __restrict__ z, const float* __restrict__ emb,
                      const int* __restrict__ idx_int, float* __restrict__ zq,
                      double* __restrict__ accum, int* __restrict__ counts)
{
    int gid = blockIdx.x * 256 + threadIdx.x;
    if (gid < M_TOT) atomicAdd(&counts[idx_int[gid]], 1);

    long base = (long)blockIdx.x * 1024 + threadIdx.x * 4;
    int m = (int)(base >> 8), d = (int)(base & 255);
    int idxm = idx_int[m];
    float4 ev = *(const float4*)&emb[(long)idxm * D_DIM + d];
    float4 zv = *(const float4*)&z[base];
    *(float4*)&zq[base] = ev;
    float dx = ev.x - zv.x, dy = ev.y - zv.y, dz = ev.z - zv.z, dw = ev.w - zv.w;
    float s = dx * dx + dy * dy + dz * dz + dw * dw;
    for (int o = 32; o > 0; o >>= 1) s += __shfl_down(s, o, 64);
    __shared__ float red[4];
    if ((threadIdx.x & 63) == 0) red[threadIdx.x >> 6] = s;
    __syncthreads();
    if (threadIdx.x == 0) atomicAdd(accum, (double)(red[0] + red[1] + red[2] + red[3]));
}

// ---------------- losses + code stats ---------------------------------------
__global__ void k_final(const float* __restrict__ code_age, const float* __restrict__ code_usage,
                        const int* __restrict__ counts, const double* __restrict__ accum,
                        float* __restrict__ out_losses, float* __restrict__ out_age,
                        float* __restrict__ out_usage)
{
    int n = blockIdx.x * 256 + threadIdx.x;
    if (n < N_E) {
        int c = counts[n];
        out_age[n] = (c > 0) ? 0.0f : code_age[n] + 1.0f;
        out_usage[n] = code_usage[n] + (float)c;
    }
    if (n == 0) {
        double mean = *accum / (double)((long)M_TOT * D_DIM);
        out_losses[0] = (float)(0.25 * mean);
        out_losses[1] = (float)mean;
    }
}

extern "C" void kernel_launch(void* const* d_in, const int* in_sizes, int n_in,
                              void* d_out, int out_size, void* d_ws, size_t ws_size,
                              hipStream_t stream) {
    const float* z          = (const float*)d_in[0];
    const float* emb        = (const float*)d_in[1];
    const float* code_age   = (const float*)d_in[2];
    const float* code_usage = (const float*)d_in[3];

    float* out        = (float*)d_out;
    float* out_zq     = out;                       // 8388608
    float* out_losses = out + 8388608;             // 2
    float* out_idx    = out + 8388610;             // 32768
    float* out_age    = out + 8388610 + M_TOT;     // 8192
    float* out_usage  = out_age + N_E;             // 8192

    char* ws = (char*)d_ws;
    _Float16* z_h   = (_Float16*)(ws);             // 16 MB
    _Float16* emb_h = (_Float16*)(ws + 16777216);  // 4 MB
    int* idx_int    = (int*)(ws + 20971520);       // 128 KB
    int* counts     = (int*)(ws + 21102592);       // 32 KB
    int* amb_list   = (int*)(ws + 21135360);       // 128 KB
    int* amb_cnt    = (int*)(ws + 21266432);       // 4
    double* accum   = (double*)(ws + 21266440);    // 8
    u64* bg         = (u64*)(ws + 21266448);       // 256 KB

    k_init<<<128, 256, 0, stream>>>(counts, amb_cnt, accum, bg);
    k_prep_emb<<<2048, 256, 0, stream>>>(emb, emb_h);
    k_prep_z<<<8192, 256, 0, stream>>>(z, z_h);
    k_argmax<<<M_TOT / BM, 256, 0, stream>>>(z_h, emb_h, out_idx, idx_int,
                                             amb_list, amb_cnt);
    k_emu<<<512, 256, 0, stream>>>(z, emb, amb_list, amb_cnt, bg);
    k_emu_write<<<32, 256, 0, stream>>>(amb_list, amb_cnt, bg, out_idx, idx_int);
    k_out<<<8192, 256, 0, stream>>>(z, emb, idx_int, out_zq, accum, counts);
    k_final<<<32, 256, 0, stream>>>(code_age, code_usage, counts, accum,
                                    out_losses, out_age, out_usage);
}

// Round 5
// 714.982 us; speedup vs baseline: 2.4279x; 2.4279x over previous
//
#include <hip/hip_runtime.h>
#include <stdint.h>

typedef unsigned int u32;
typedef unsigned long long u64;
typedef _Float16 half8 __attribute__((ext_vector_type(8)));
typedef _Float16 half4 __attribute__((ext_vector_type(4)));
typedef float f32x4 __attribute__((ext_vector_type(4)));

#define M_TOT 32768
#define D_DIM 256
#define N_E   8192
#define BM 64
#define BN 256
#define SA 264
#define SB 40
// flag margin in RAW f16-acc units (validated PASS in round 4)
#define MARGIN_RAW 0.16384f
// candidate margin in dot units: ulp(q)/2 (1.53e-5) + 4sigma screen err (5.4e-6) + slack
#define CAND_MARGIN 3.0e-5f
#define RAW2DOT 1.220703125e-4f   // 1/8192
#define CAND_MAX 65536

__device__ __forceinline__ u32 umax32(u32 a, u32 b) { return a > b ? a : b; }
__device__ __forceinline__ u32 umin32(u32 a, u32 b) { return a < b ? a : b; }
__device__ __forceinline__ u64 umax64(u64 a, u64 b) { return a > b ? a : b; }
__device__ __forceinline__ u64 umin64(u64 a, u64 b) { return a < b ? a : b; }

__device__ __forceinline__ u32 map_f32(float f) {
    u32 u = __float_as_uint(f);
    return u ^ ((u32)((int)u >> 31) | 0x80000000u);
}
__device__ __forceinline__ float unmap_f32(u32 u) {
    return __uint_as_float(u ^ ((u & 0x80000000u) ? 0x80000000u : 0xFFFFFFFFu));
}

// ---------------- init ------------------------------------------------------
__global__ void k_init(int* counts, int* amb_cnt, double* accum, u64* bg, int* cand_cnt) {
    int i = blockIdx.x * 256 + threadIdx.x;
    if (i < M_TOT) bg[i] = ~0ull;
    if (i < N_E) counts[i] = 0;
    if (i == 0) { *amb_cnt = 0; *accum = 0.0; *cand_cnt = 0; }
}

// ---------------- emb -> f16 scaled x8192 (exact pow2) ----------------------
__global__ void k_prep_emb(const float* __restrict__ emb, _Float16* __restrict__ emb_h) {
    long i = (long)blockIdx.x * 1024 + threadIdx.x * 4;
    float4 v = *(const float4*)(emb + i);
    half4 h = { (_Float16)(v.x * 8192.0f), (_Float16)(v.y * 8192.0f),
                (_Float16)(v.z * 8192.0f), (_Float16)(v.w * 8192.0f) };
    *(half4*)(emb_h + i) = h;
}

// ---------------- z -> f16 --------------------------------------------------
__global__ void k_prep_z(const float* __restrict__ z, _Float16* __restrict__ z_h) {
    long i = (long)blockIdx.x * 1024 + threadIdx.x * 4;
    float4 v = *(const float4*)(z + i);
    half4 h = { (_Float16)v.x, (_Float16)v.y, (_Float16)v.z, (_Float16)v.w };
    *(half4*)(z_h + i) = h;
}

// ---------------- f16 MFMA screen: argmax(dot) + top-2 gap flag -------------
__global__ __launch_bounds__(256, 2) void k_argmax(
    const _Float16* __restrict__ z_h, const _Float16* __restrict__ emb_h,
    float* __restrict__ out_idx_f, int* __restrict__ idx_int,
    int* __restrict__ amb_list, int* __restrict__ amb_cnt, float* __restrict__ smax)
{
    __shared__ _Float16 As[BM * SA];
    __shared__ _Float16 Bs[BN * SB];
    __shared__ u64 redB1[4][BM];
    __shared__ u32 redB2[4][BM];

    const int t = threadIdx.x;
    const int w = t >> 6;
    const int lane = t & 63;
    const int quad = lane >> 4;
    const int l15 = lane & 15;
    const int m0 = blockIdx.x * BM;
    const int wn = w * 64;

    #pragma unroll
    for (int i = 0; i < 8; ++i) {
        int c = i * 256 + t;
        int row = c >> 5, seg = c & 31;
        *(half8*)&As[row * SA + seg * 8] = *(const half8*)&z_h[(long)(m0 + row) * D_DIM + seg * 8];
    }

    f32x4 acc[4][4];
    u64 B1[16];
    u32 B2[16];
    #pragma unroll
    for (int g = 0; g < 16; ++g) { B1[g] = 0ull; B2[g] = 0u; }

    for (int nt = 0; nt < N_E / BN; ++nt) {
        const int n0 = nt * BN;
        #pragma unroll
        for (int mi = 0; mi < 4; ++mi)
            #pragma unroll
            for (int ni = 0; ni < 4; ++ni)
                acc[mi][ni] = (f32x4){0.f, 0.f, 0.f, 0.f};

        for (int ks = 0; ks < 8; ++ks) {
            __syncthreads();
            #pragma unroll
            for (int i = 0; i < 4; ++i) {
                int c = i * 256 + t;
                int col = c >> 2, seg = c & 3;
                *(half8*)&Bs[col * SB + seg * 8] =
                    *(const half8*)&emb_h[(long)(n0 + col) * D_DIM + ks * 32 + seg * 8];
            }
            __syncthreads();
            half8 af[4], bf[4];
            #pragma unroll
            for (int mi = 0; mi < 4; ++mi)
                af[mi] = *(const half8*)&As[(mi * 16 + l15) * SA + ks * 32 + quad * 8];
            #pragma unroll
            for (int ni = 0; ni < 4; ++ni)
                bf[ni] = *(const half8*)&Bs[(wn + ni * 16 + l15) * SB + quad * 8];
            #pragma unroll
            for (int mi = 0; mi < 4; ++mi)
                #pragma unroll
                for (int ni = 0; ni < 4; ++ni)
                    acc[mi][ni] = __builtin_amdgcn_mfma_f32_16x16x32_f16(af[mi], bf[ni], acc[mi][ni], 0, 0, 0);
        }

        u32 idxw[4];
        #pragma unroll
        for (int ni = 0; ni < 4; ++ni)
            idxw[ni] = (u32)(N_E - 1 - (n0 + wn + ni * 16 + l15));
        #pragma unroll
        for (int mi = 0; mi < 4; ++mi) {
            #pragma unroll
            for (int reg = 0; reg < 4; ++reg) {
                u32 s[4]; u64 p[4];
                #pragma unroll
                for (int ni = 0; ni < 4; ++ni) {
                    s[ni] = map_f32(acc[mi][ni][reg]);
                    p[ni] = ((u64)s[ni] << 32) | (u64)idxw[ni];
                }
                u64 t1 = umax64(umax64(p[0], p[1]), umax64(p[2], p[3]));
                u32 a = umax32(s[0], s[1]), b = umin32(s[0], s[1]);
                u32 c = umax32(s[2], s[3]), d = umin32(s[2], s[3]);
                u32 t2 = umax32(umin32(a, c), umax32(b, d));
                int g = mi * 4 + reg;
                u32 b1s = (u32)(B1[g] >> 32), t1s = (u32)(t1 >> 32);
                B2[g] = umax32(umax32(B2[g], t2), umin32(b1s, t1s));
                B1[g] = umax64(B1[g], t1);
            }
        }
    }

    #pragma unroll
    for (int g = 0; g < 16; ++g) {
        u64 b1 = B1[g]; u32 b2 = B2[g];
        for (int o = 1; o < 16; o <<= 1) {
            u64 ob1 = __shfl_xor(b1, o, 64);
            u32 ob2 = __shfl_xor(b2, o, 64);
            u32 s1 = (u32)(b1 >> 32), so = (u32)(ob1 >> 32);
            b2 = umax32(umax32(b2, ob2), umin32(s1, so));
            b1 = umax64(b1, ob1);
        }
        B1[g] = b1; B2[g] = b2;
    }
    if (l15 == 0) {
        #pragma unroll
        for (int g = 0; g < 16; ++g) {
            int mi = g >> 2, reg = g & 3;
            int r = mi * 16 + quad * 4 + reg;
            redB1[w][r] = B1[g];
            redB2[w][r] = B2[g];
        }
    }
    __syncthreads();
    if (t < BM) {
        u64 b1 = 0ull; u32 b2 = 0u;
        #pragma unroll
        for (int ww = 0; ww < 4; ++ww) {
            u64 v1 = redB1[ww][t]; u32 v2 = redB2[ww][t];
            u32 s1 = (u32)(b1 >> 32), so = (u32)(v1 >> 32);
            b2 = umax32(umax32(b2, v2), umin32(s1, so));
            b1 = umax64(b1, v1);
        }
        int idx = (int)(N_E - 1 - (u32)(b1 & 0xFFFFFFFFu));
        int m = m0 + t;
        out_idx_f[m] = (float)idx;
        idx_int[m] = idx;
        smax[m] = unmap_f32((u32)(b1 >> 32));   // best raw f16 dot (scaled x8192)
        float gap = unmap_f32((u32)(b1 >> 32)) - unmap_f32(b2);
        if (gap < MARGIN_RAW) {
            int p = atomicAdd(amb_cnt, 1);
            if (p < M_TOT) amb_list[p] = m;
        }
    }
}

// ---------------- phase A: fp32 rescore of flagged rows, collect candidates -
// 8x8 micro-tile (round-2 structure, 125 TF measured). unit = 64-row group x
// 512-col slice. Collect (m,n) where dot >= smax*1/8192 - CAND_MARGIN.
__global__ __launch_bounds__(256, 2) void k_cand(
    const float* __restrict__ z, const float* __restrict__ emb,
    const float* __restrict__ smax, const int* __restrict__ amb_list,
    const int* __restrict__ amb_cnt, u64* __restrict__ cand, int* __restrict__ cand_cnt)
{
    __shared__ __align__(16) float zt[64 * D_DIM];   // 64 KB
    __shared__ int ml[64];
    __shared__ float dmax_s[64];
    int cnt = *amb_cnt; if (cnt > M_TOT) cnt = M_TOT;
    const int t = threadIdx.x;
    const int ty = t >> 5, tx = t & 31;
    const int ngroups = (cnt + 63) >> 6;
    const int nunits = ngroups * 16;

    for (int u = blockIdx.x; u < nunits; u += gridDim.x) {
        const int g = u >> 4, slice = u & 15;
        __syncthreads();
        if (t < 64) {
            int gi = g * 64 + t;
            int mm = amb_list[gi < cnt ? gi : cnt - 1];
            ml[t] = mm;
            dmax_s[t] = smax[mm] * RAW2DOT;
        }
        __syncthreads();
        for (int i = 0; i < 16; ++i) {
            int c = i * 256 + t;
            int row = c >> 6, w4 = c & 63;
            *(float4*)&zt[row * D_DIM + w4 * 4] =
                *(const float4*)&z[(long)ml[row] * D_DIM + w4 * 4];
        }
        __syncthreads();

        for (int ch = 0; ch < 2; ++ch) {
            const int ncol0 = slice * 512 + ch * 256;
            float acc[8][8];
            #pragma unroll
            for (int r = 0; r < 8; ++r)
                #pragma unroll
                for (int j = 0; j < 8; ++j) acc[r][j] = 0.0f;

            const float* ebase = emb + (long)(ncol0 + tx * 8) * D_DIM;
            for (int kq = 0; kq < 64; ++kq) {
                float4 e4[8], z4[8];
                #pragma unroll
                for (int j = 0; j < 8; ++j)
                    e4[j] = *(const float4*)(ebase + j * D_DIM + kq * 4);
                #pragma unroll
                for (int r = 0; r < 8; ++r)
                    z4[r] = *(const float4*)&zt[(ty * 8 + r) * D_DIM + kq * 4];
                #pragma unroll
                for (int r = 0; r < 8; ++r)
                    #pragma unroll
                    for (int j = 0; j < 8; ++j) {
                        float a = acc[r][j];
                        a = fmaf(z4[r].x, e4[j].x, a);
                        a = fmaf(z4[r].y, e4[j].y, a);
                        a = fmaf(z4[r].z, e4[j].z, a);
                        a = fmaf(z4[r].w, e4[j].w, a);
                        acc[r][j] = a;
                    }
            }
            #pragma unroll
            for (int r = 0; r < 8; ++r) {
                float thr = dmax_s[ty * 8 + r] - CAND_MARGIN;
                #pragma unroll
                for (int j = 0; j < 8; ++j) {
                    if (acc[r][j] >= thr) {
                        int p = atomicAdd(cand_cnt, 1);
                        if (p < CAND_MAX)
                            cand[p] = ((u64)(u32)ml[ty * 8 + r] << 32) | (u32)(ncol0 + tx * 8 + j);
                    }
                }
            }
        }
    }
}

// ---------------- phase B: bitwise np-fp32 exact per candidate --------------
// q = fl(z2_np - 2*dot_np); dot = numpy einsum baseline-SSE order (4 lanes,
// 16-elem iters, muladd chain unfused, hsum (s0+s1)+(s2+s3)). Validated r4.
__global__ void k_exact(const float* __restrict__ z, const float* __restrict__ emb,
                        const u64* __restrict__ cand, const int* __restrict__ cand_cnt,
                        u64* __restrict__ bg)
{
    #pragma clang fp contract(off)
    int cc = *cand_cnt; if (cc > CAND_MAX) cc = CAND_MAX;
    int i = blockIdx.x * 256 + threadIdx.x;
    if (i >= cc) return;
    u64 cd = cand[i];
    int m = (int)(cd >> 32), n = (int)(cd & 0xFFFFFFFFu);
    const float* zp = z + (long)m * D_DIM;
    const float* ep = emb + (long)n * D_DIM;

    // z2: numpy pairwise (256 = 128+128, 8 accumulators)
    float z2 = 0.0f;
    for (int h = 0; h < 2; ++h) {
        const float* p = zp + h * 128;
        float r0 = p[0]*p[0], r1 = p[1]*p[1], r2 = p[2]*p[2], r3 = p[3]*p[3];
        float r4 = p[4]*p[4], r5 = p[5]*p[5], r6 = p[6]*p[6], r7 = p[7]*p[7];
        for (int k = 8; k < 128; k += 8) {
            r0 += p[k+0]*p[k+0]; r1 += p[k+1]*p[k+1];
            r2 += p[k+2]*p[k+2]; r3 += p[k+3]*p[k+3];
            r4 += p[k+4]*p[k+4]; r5 += p[k+5]*p[k+5];
            r6 += p[k+6]*p[k+6]; r7 += p[k+7]*p[k+7];
        }
        z2 = z2 + (((r0 + r1) + (r2 + r3)) + ((r4 + r5) + (r6 + r7)));
    }
    // SSE einsum dot
    float v0 = 0.f, v1 = 0.f, v2 = 0.f, v3 = 0.f;
    for (int it = 0; it < 16; ++it) {
        const float* zz = zp + it * 16;
        const float* ee = ep + it * 16;
        v0 = zz[0]*ee[0] + (zz[4]*ee[4] + (zz[8]*ee[8] + (zz[12]*ee[12] + v0)));
        v1 = zz[1]*ee[1] + (zz[5]*ee[5] + (zz[9]*ee[9] + (zz[13]*ee[13] + v1)));
        v2 = zz[2]*ee[2] + (zz[6]*ee[6] + (zz[10]*ee[10] + (zz[14]*ee[14] + v2)));
        v3 = zz[3]*ee[3] + (zz[7]*ee[7] + (zz[11]*ee[11] + (zz[15]*ee[15] + v3)));
    }
    float dot = (v0 + v1) + (v2 + v3);
    float q = z2 - 2.0f * dot;
    atomicMin(&bg[m], ((u64)map_f32(q) << 32) | (u64)(u32)n);
}

// ---------------- write back emulated winners -------------------------------
__global__ void k_emu_write(const int* __restrict__ amb_list, const int* __restrict__ amb_cnt,
                            const u64* __restrict__ bg,
                            float* __restrict__ out_idx_f, int* __restrict__ idx_int)
{
    int cnt = *amb_cnt; if (cnt > M_TOT) cnt = M_TOT;
    for (int i = blockIdx.x * 256 + threadIdx.x; i < cnt; i += gridDim.x * 256) {
        int m = amb_list[i];
        u64 b = bg[m];
        if (b != ~0ull) {
            int n = (int)(b & 0xFFFFFFFFu);
            out_idx_f[m] = (float)n;
            idx_int[m] = n;
        }
    }
}

// ---------------- z_q gather + sum(diff^2) + histogram ----------------------
__global__ void k_out(const float* __restrict__ z, const float* __restrict__ emb,
                      const int* __restrict__ idx_int, float* __restrict__ zq,
                      double* __restrict__ accum, int* __restrict__ counts)
{
    int gid = blockIdx.x * 256 + threadIdx.x;
    if (gid < M_TOT) atomicAdd(&counts[idx_int[gid]], 1);

    long base = (long)blockIdx.x * 1024 + threadIdx.x * 4;
    int m = (int)(base >> 8), d = (int)(base & 255);
    int idxm = idx_int[m];
    float4 ev = *(const float4*)&emb[(long)idxm * D_DIM + d];
    float4 zv = *(const float4*)&z[base];
    *(float4*)&zq[base] = ev;
    float dx = ev.x - zv.x, dy = ev.y - zv.y, dz = ev.z - zv.z, dw = ev.w - zv.w;
    float s = dx * dx + dy * dy + dz * dz + dw * dw;
    for (int o = 32; o > 0; o >>= 1) s += __shfl_down(s, o, 64);
    __shared__ float red[4];
    if ((threadIdx.x & 63) == 0) red[threadIdx.x >> 6] = s;
    __syncthreads();
    if (threadIdx.x == 0) atomicAdd(accum, (double)(red[0] + red[1] + red[2] + red[3]));
}

// ---------------- losses + code stats ---------------------------------------
__global__ void k_final(const float* __restrict__ code_age, const float* __restrict__ code_usage,
                        const int* __restrict__ counts, const double* __restrict__ accum,
                        float* __restrict__ out_losses, float* __restrict__ out_age,
                        float* __restrict__ out_usage)
{
    int n = blockIdx.x * 256 + threadIdx.x;
    if (n < N_E) {
        int c = counts[n];
        out_age[n] = (c > 0) ? 0.0f : code_age[n] + 1.0f;
        out_usage[n] = code_usage[n] + (float)c;
    }
    if (n == 0) {
        double mean = *accum / (double)((long)M_TOT * D_DIM);
        out_losses[0] = (float)(0.25 * mean);
        out_losses[1] = (float)mean;
    }
}

extern "C" void kernel_launch(void* const* d_in, const int* in_sizes, int n_in,
                              void* d_out, int out_size, void* d_ws, size_t ws_size,
                              hipStream_t stream) {
    const float* z          = (const float*)d_in[0];
    const float* emb        = (const float*)d_in[1];
    const float* code_age   = (const float*)d_in[2];
    const float* code_usage = (const float*)d_in[3];

    float* out        = (float*)d_out;
    float* out_zq     = out;                       // 8388608
    float* out_losses = out + 8388608;             // 2
    float* out_idx    = out + 8388610;             // 32768
    float* out_age    = out + 8388610 + M_TOT;     // 8192
    float* out_usage  = out_age + N_E;             // 8192

    char* ws = (char*)d_ws;
    _Float16* z_h   = (_Float16*)(ws);             // 16 MB
    _Float16* emb_h = (_Float16*)(ws + 16777216);  // 4 MB
    int* idx_int    = (int*)(ws + 20971520);       // 128 KB
    int* counts     = (int*)(ws + 21102592);       // 32 KB
    int* amb_list   = (int*)(ws + 21135360);       // 128 KB
    int* amb_cnt    = (int*)(ws + 21266432);       // 4 (+4)
    double* accum   = (double*)(ws + 21266440);    // 8
    u64* bg         = (u64*)(ws + 21266448);       // 256 KB
    float* smax     = (float*)(ws + 21528592);     // 128 KB
    u64* cand       = (u64*)(ws + 21659664);       // 512 KB
    int* cand_cnt   = (int*)(ws + 22183952);       // 4

    k_init<<<128, 256, 0, stream>>>(counts, amb_cnt, accum, bg, cand_cnt);
    k_prep_emb<<<2048, 256, 0, stream>>>(emb, emb_h);
    k_prep_z<<<8192, 256, 0, stream>>>(z, z_h);
    k_argmax<<<M_TOT / BM, 256, 0, stream>>>(z_h, emb_h, out_idx, idx_int,
                                             amb_list, amb_cnt, smax);
    k_cand<<<768, 256, 0, stream>>>(z, emb, smax, amb_list, amb_cnt, cand, cand_cnt);
    k_exact<<<256, 256, 0, stream>>>(z, emb, cand, cand_cnt, bg);
    k_emu_write<<<32, 256, 0, stream>>>(amb_list, amb_cnt, bg, out_idx, idx_int);
    k_out<<<8192, 256, 0, stream>>>(z, emb, idx_int, out_zq, accum, counts);
    k_final<<<32, 256, 0, stream>>>(code_age, code_usage, counts, accum,
                                    out_losses, out_age, out_usage);
}

// Round 7
// 491.039 us; speedup vs baseline: 3.5352x; 1.4561x over previous
//
#include <hip/hip_runtime.h>
#include <stdint.h>

typedef unsigned int u32;
typedef unsigned long long u64;
typedef _Float16 half8 __attribute__((ext_vector_type(8)));
typedef _Float16 half4 __attribute__((ext_vector_type(4)));
typedef float f32x4 __attribute__((ext_vector_type(4)));

#define M_TOT 32768
#define D_DIM 256
#define N_E   8192
#define BM 64
#define BN 256
#define SA 264
#define SB 40
// flag margin in RAW f16-acc units (validated PASS rounds 4/5)
#define MARGIN_RAW 0.16384f
// rescan candidate margin, RAW units: 0.125 (ulp(q)/2) + ~9.5 sigma noise (0.011) + slack
#define CAND_MARGIN2_RAW 0.35f
#define CAND_MAX 65536

__device__ __forceinline__ u32 umax32(u32 a, u32 b) { return a > b ? a : b; }
__device__ __forceinline__ u32 umin32(u32 a, u32 b) { return a < b ? a : b; }
__device__ __forceinline__ u64 umax64(u64 a, u64 b) { return a > b ? a : b; }

__device__ __forceinline__ u32 map_f32(float f) {
    u32 u = __float_as_uint(f);
    return u ^ ((u32)((int)u >> 31) | 0x80000000u);
}
__device__ __forceinline__ float unmap_f32(u32 u) {
    return __uint_as_float(u ^ ((u & 0x80000000u) ? 0x80000000u : 0xFFFFFFFFu));
}

// ---------------- init ------------------------------------------------------
__global__ void k_init(int* counts, int* amb_cnt, double* accum, u64* bg, int* cand_cnt) {
    int i = blockIdx.x * 256 + threadIdx.x;
    if (i < M_TOT) bg[i] = ~0ull;
    if (i < N_E) counts[i] = 0;
    if (i == 0) { *amb_cnt = 0; *accum = 0.0; *cand_cnt = 0; }
}

// ---------------- emb -> f16 scaled x8192 (exact pow2) ----------------------
__global__ void k_prep_emb(const float* __restrict__ emb, _Float16* __restrict__ emb_h) {
    long i = (long)blockIdx.x * 1024 + threadIdx.x * 4;
    float4 v = *(const float4*)(emb + i);
    half4 h = { (_Float16)(v.x * 8192.0f), (_Float16)(v.y * 8192.0f),
                (_Float16)(v.z * 8192.0f), (_Float16)(v.w * 8192.0f) };
    *(half4*)(emb_h + i) = h;
}

// ---------------- z -> f16 --------------------------------------------------
__global__ void k_prep_z(const float* __restrict__ z, _Float16* __restrict__ z_h) {
    long i = (long)blockIdx.x * 1024 + threadIdx.x * 4;
    float4 v = *(const float4*)(z + i);
    half4 h = { (_Float16)v.x, (_Float16)v.y, (_Float16)v.z, (_Float16)v.w };
    *(half4*)(z_h + i) = h;
}

// ---------------- f16 MFMA screen: argmax(dot) + top-2 gap flag + smax ------
// (round-5 kernel, verbatim — validated PASS)
__global__ __launch_bounds__(256, 2) void k_argmax(
    const _Float16* __restrict__ z_h, const _Float16* __restrict__ emb_h,
    float* __restrict__ out_idx_f, int* __restrict__ idx_int,
    int* __restrict__ amb_list, int* __restrict__ amb_cnt, float* __restrict__ smax)
{
    __shared__ _Float16 As[BM * SA];
    __shared__ _Float16 Bs[BN * SB];
    __shared__ u64 redB1[4][BM];
    __shared__ u32 redB2[4][BM];

    const int t = threadIdx.x;
    const int w = t >> 6;
    const int lane = t & 63;
    const int quad = lane >> 4;
    const int l15 = lane & 15;
    const int m0 = blockIdx.x * BM;
    const int wn = w * 64;

    #pragma unroll
    for (int i = 0; i < 8; ++i) {
        int c = i * 256 + t;
        int row = c >> 5, seg = c & 31;
        *(half8*)&As[row * SA + seg * 8] = *(const half8*)&z_h[(long)(m0 + row) * D_DIM + seg * 8];
    }

    f32x4 acc[4][4];
    u64 B1[16];
    u32 B2[16];
    #pragma unroll
    for (int g = 0; g < 16; ++g) { B1[g] = 0ull; B2[g] = 0u; }

    for (int nt = 0; nt < N_E / BN; ++nt) {
        const int n0 = nt * BN;
        #pragma unroll
        for (int mi = 0; mi < 4; ++mi)
            #pragma unroll
            for (int ni = 0; ni < 4; ++ni)
                acc[mi][ni] = (f32x4){0.f, 0.f, 0.f, 0.f};

        for (int ks = 0; ks < 8; ++ks) {
            __syncthreads();
            #pragma unroll
            for (int i = 0; i < 4; ++i) {
                int c = i * 256 + t;
                int col = c >> 2, seg = c & 3;
                *(half8*)&Bs[col * SB + seg * 8] =
                    *(const half8*)&emb_h[(long)(n0 + col) * D_DIM + ks * 32 + seg * 8];
            }
            __syncthreads();
            half8 af[4], bf[4];
            #pragma unroll
            for (int mi = 0; mi < 4; ++mi)
                af[mi] = *(const half8*)&As[(mi * 16 + l15) * SA + ks * 32 + quad * 8];
            #pragma unroll
            for (int ni = 0; ni < 4; ++ni)
                bf[ni] = *(const half8*)&Bs[(wn + ni * 16 + l15) * SB + quad * 8];
            #pragma unroll
            for (int mi = 0; mi < 4; ++mi)
                #pragma unroll
                for (int ni = 0; ni < 4; ++ni)
                    acc[mi][ni] = __builtin_amdgcn_mfma_f32_16x16x32_f16(af[mi], bf[ni], acc[mi][ni], 0, 0, 0);
        }

        u32 idxw[4];
        #pragma unroll
        for (int ni = 0; ni < 4; ++ni)
            idxw[ni] = (u32)(N_E - 1 - (n0 + wn + ni * 16 + l15));
        #pragma unroll
        for (int mi = 0; mi < 4; ++mi) {
            #pragma unroll
            for (int reg = 0; reg < 4; ++reg) {
                u32 s[4]; u64 p[4];
                #pragma unroll
                for (int ni = 0; ni < 4; ++ni) {
                    s[ni] = map_f32(acc[mi][ni][reg]);
                    p[ni] = ((u64)s[ni] << 32) | (u64)idxw[ni];
                }
                u64 t1 = umax64(umax64(p[0], p[1]), umax64(p[2], p[3]));
                u32 a = umax32(s[0], s[1]), b = umin32(s[0], s[1]);
                u32 c = umax32(s[2], s[3]), d = umin32(s[2], s[3]);
                u32 t2 = umax32(umin32(a, c), umax32(b, d));
                int g = mi * 4 + reg;
                u32 b1s = (u32)(B1[g] >> 32), t1s = (u32)(t1 >> 32);
                B2[g] = umax32(umax32(B2[g], t2), umin32(b1s, t1s));
                B1[g] = umax64(B1[g], t1);
            }
        }
    }

    #pragma unroll
    for (int g = 0; g < 16; ++g) {
        u64 b1 = B1[g]; u32 b2 = B2[g];
        for (int o = 1; o < 16; o <<= 1) {
            u64 ob1 = __shfl_xor(b1, o, 64);
            u32 ob2 = __shfl_xor(b2, o, 64);
            u32 s1 = (u32)(b1 >> 32), so = (u32)(ob1 >> 32);
            b2 = umax32(umax32(b2, ob2), umin32(s1, so));
            b1 = umax64(b1, ob1);
        }
        B1[g] = b1; B2[g] = b2;
    }
    if (l15 == 0) {
        #pragma unroll
        for (int g = 0; g < 16; ++g) {
            int mi = g >> 2, reg = g & 3;
            int r = mi * 16 + quad * 4 + reg;
            redB1[w][r] = B1[g];
            redB2[w][r] = B2[g];
        }
    }
    __syncthreads();
    if (t < BM) {
        u64 b1 = 0ull; u32 b2 = 0u;
        #pragma unroll
        for (int ww = 0; ww < 4; ++ww) {
            u64 v1 = redB1[ww][t]; u32 v2 = redB2[ww][t];
            u32 s1 = (u32)(b1 >> 32), so = (u32)(v1 >> 32);
            b2 = umax32(umax32(b2, v2), umin32(s1, so));
            b1 = umax64(b1, v1);
        }
        int idx = (int)(N_E - 1 - (u32)(b1 & 0xFFFFFFFFu));
        int m = m0 + t;
        out_idx_f[m] = (float)idx;
        idx_int[m] = idx;
        smax[m] = unmap_f32((u32)(b1 >> 32));
        float gap = unmap_f32((u32)(b1 >> 32)) - unmap_f32(b2);
        if (gap < MARGIN_RAW) {
            int p = atomicAdd(amb_cnt, 1);
            if (p < M_TOT) amb_list[p] = m;
        }
    }
}

// ---------------- f16 MFMA rescan of flagged rows -> candidates -------------
// unit = (64 flagged rows) x (1024-col slice). Same MFMA engine as screen;
// emit (m,n) where score >= smax[m] - 0.35 raw. Row's own max always re-found
// => >=1 candidate per flagged row guaranteed.
__global__ __launch_bounds__(256, 2) void k_cand(
    const _Float16* __restrict__ z_h, const _Float16* __restrict__ emb_h,
    const float* __restrict__ smax, const int* __restrict__ amb_list,
    const int* __restrict__ amb_cnt, u32* __restrict__ cand, int* __restrict__ cand_cnt)
{
    __shared__ _Float16 As[BM * SA];
    __shared__ _Float16 Bs[BN * SB];
    __shared__ int ml[64];
    __shared__ float thr_s[64];

    int cnt = *amb_cnt; if (cnt > M_TOT) cnt = M_TOT;
    const int ngroups = (cnt + 63) >> 6;
    const int nunits = ngroups * 8;
    const int t = threadIdx.x;
    const int w = t >> 6, lane = t & 63, quad = lane >> 4, l15 = lane & 15;
    const int wn = w * 64;

    for (int u = blockIdx.x; u < nunits; u += gridDim.x) {
        const int g = u >> 3, slice = u & 7;
        __syncthreads();   // protect ml/As reuse from previous unit
        if (t < 64) {
            int gi = g * 64 + t;
            int mm = amb_list[gi < cnt ? gi : cnt - 1];
            ml[t] = mm;
            thr_s[t] = smax[mm] - CAND_MARGIN2_RAW;
        }
        __syncthreads();
        #pragma unroll
        for (int i = 0; i < 8; ++i) {
            int c = i * 256 + t;
            int row = c >> 5, seg = c & 31;
            *(half8*)&As[row * SA + seg * 8] =
                *(const half8*)&z_h[(long)ml[row] * D_DIM + seg * 8];
        }

        for (int st = 0; st < 4; ++st) {
            const int n0 = slice * 1024 + st * 256;
            f32x4 acc[4][4];
            #pragma unroll
            for (int mi = 0; mi < 4; ++mi)
                #pragma unroll
                for (int ni = 0; ni < 4; ++ni)
                    acc[mi][ni] = (f32x4){0.f, 0.f, 0.f, 0.f};

            for (int ks = 0; ks < 8; ++ks) {
                __syncthreads();
                #pragma unroll
                for (int i = 0; i < 4; ++i) {
                    int c = i * 256 + t;
                    int col = c >> 2, seg = c & 3;
                    *(half8*)&Bs[col * SB + seg * 8] =
                        *(const half8*)&emb_h[(long)(n0 + col) * D_DIM + ks * 32 + seg * 8];
                }
                __syncthreads();
                half8 af[4], bf[4];
                #pragma unroll
                for (int mi = 0; mi < 4; ++mi)
                    af[mi] = *(const half8*)&As[(mi * 16 + l15) * SA + ks * 32 + quad * 8];
                #pragma unroll
                for (int ni = 0; ni < 4; ++ni)
                    bf[ni] = *(const half8*)&Bs[(wn + ni * 16 + l15) * SB + quad * 8];
                #pragma unroll
                for (int mi = 0; mi < 4; ++mi)
                    #pragma unroll
                    for (int ni = 0; ni < 4; ++ni)
                        acc[mi][ni] = __builtin_amdgcn_mfma_f32_16x16x32_f16(af[mi], bf[ni], acc[mi][ni], 0, 0, 0);
            }

            #pragma unroll
            for (int mi = 0; mi < 4; ++mi) {
                #pragma unroll
                for (int reg = 0; reg < 4; ++reg) {
                    int r = mi * 16 + quad * 4 + reg;
                    float th = thr_s[r];
                    u32 mm = (u32)ml[r];
                    #pragma unroll
                    for (int ni = 0; ni < 4; ++ni) {
                        if (acc[mi][ni][reg] >= th) {
                            u32 n = (u32)(n0 + wn + ni * 16 + l15);
                            int p = atomicAdd(cand_cnt, 1);
                            if (p < CAND_MAX) cand[p] = (mm << 13) | n;
                        }
                    }
                }
            }
        }
    }
}

// ---------------- bitwise np-fp32 exact per candidate -----------------------
// q = fl(z2_np - 2*dot_np); dot = numpy einsum baseline-SSE order (validated
// rounds 4/5). atomicMin picks np argmin w/ first-index tie-break.
__global__ void k_exact(const float* __restrict__ z, const float* __restrict__ emb,
                        const u32* __restrict__ cand, const int* __restrict__ cand_cnt,
                        u64* __restrict__ bg)
{
    #pragma clang fp contract(off)
    int cc = *cand_cnt; if (cc > CAND_MAX) cc = CAND_MAX;
    int i = blockIdx.x * 256 + threadIdx.x;
    if (i >= cc) return;
    u32 cd = cand[i];
    int m = (int)(cd >> 13), n = (int)(cd & 8191u);
    const float* zp = z + (long)m * D_DIM;
    const float* ep = emb + (long)n * D_DIM;

    float z2 = 0.0f;
    for (int h = 0; h < 2; ++h) {
        const float* p = zp + h * 128;
        float r0 = p[0]*p[0], r1 = p[1]*p[1], r2 = p[2]*p[2], r3 = p[3]*p[3];
        float r4 = p[4]*p[4], r5 = p[5]*p[5], r6 = p[6]*p[6], r7 = p[7]*p[7];
        for (int k = 8; k < 128; k += 8) {
            r0 += p[k+0]*p[k+0]; r1 += p[k+1]*p[k+1];
            r2 += p[k+2]*p[k+2]; r3 += p[k+3]*p[k+3];
            r4 += p[k+4]*p[k+4]; r5 += p[k+5]*p[k+5];
            r6 += p[k+6]*p[k+6]; r7 += p[k+7]*p[k+7];
        }
        z2 = z2 + (((r0 + r1) + (r2 + r3)) + ((r4 + r5) + (r6 + r7)));
    }
    float v0 = 0.f, v1 = 0.f, v2 = 0.f, v3 = 0.f;
    for (int it = 0; it < 16; ++it) {
        const float* zz = zp + it * 16;
        const float* ee = ep + it * 16;
        v0 = zz[0]*ee[0] + (zz[4]*ee[4] + (zz[8]*ee[8] + (zz[12]*ee[12] + v0)));
        v1 = zz[1]*ee[1] + (zz[5]*ee[5] + (zz[9]*ee[9] + (zz[13]*ee[13] + v1)));
        v2 = zz[2]*ee[2] + (zz[6]*ee[6] + (zz[10]*ee[10] + (zz[14]*ee[14] + v2)));
        v3 = zz[3]*ee[3] + (zz[7]*ee[7] + (zz[11]*ee[11] + (zz[15]*ee[15] + v3)));
    }
    float dot = (v0 + v1) + (v2 + v3);
    float q = z2 - 2.0f * dot;
    atomicMin(&bg[m], ((u64)map_f32(q) << 32) | (u64)(u32)n);
}

// ---------------- write back exact winners (flagged rows only) --------------
__global__ void k_emu_write(const int* __restrict__ amb_list, const int* __restrict__ amb_cnt,
                            const u64* __restrict__ bg,
                            float* __restrict__ out_idx_f, int* __restrict__ idx_int)
{
    int cnt = *amb_cnt; if (cnt > M_TOT) cnt = M_TOT;
    for (int i = blockIdx.x * 256 + threadIdx.x; i < cnt; i += gridDim.x * 256) {
        int m = amb_list[i];
        u64 b = bg[m];
        if (b != ~0ull) {
            int n = (int)(b & 0xFFFFFFFFu);
            out_idx_f[m] = (float)n;
            idx_int[m] = n;
        }
    }
}

// ---------------- z_q gather + sum(diff^2) + histogram ----------------------
__global__ void k_out(const float* __restrict__ z, const float* __restrict__ emb,
                      const int* __restrict__ idx_int, float* __restrict__ zq,
                      double* __restrict__ accum, int* __restrict__ counts)
{
    int gid = blockIdx.x * 256 + threadIdx.x;
    if (gid < M_TOT) atomicAdd(&counts[idx_int[gid]], 1);

    long base = (long)blockIdx.x * 1024 + threadIdx.x * 4;
    int m = (int)(base >> 8), d = (int)(base & 255);
    int idxm = idx_int[m];
    float4 ev = *(const float4*)&emb[(long)idxm * D_DIM + d];
    float4 zv = *(const float4*)&z[base];
    *(float4*)&zq[base] = ev;
    float dx = ev.x - zv.x, dy = ev.y - zv.y, dz = ev.z - zv.z, dw = ev.w - zv.w;
    float s = dx * dx + dy * dy + dz * dz + dw * dw;
    for (int o = 32; o > 0; o >>= 1) s += __shfl_down(s, o, 64);
    __shared__ float red[4];
    if ((threadIdx.x & 63) == 0) red[threadIdx.x >> 6] = s;
    __syncthreads();
    if (threadIdx.x == 0) atomicAdd(accum, (double)(red[0] + red[1] + red[2] + red[3]));
}

// ---------------- losses + code stats ---------------------------------------
__global__ void k_final(const float* __restrict__ code_age, const float* __restrict__ code_usage,
                        const int* __restrict__ counts, const double* __restrict__ accum,
                        float* __restrict__ out_losses, float* __restrict__ out_age,
                        float* __restrict__ out_usage)
{
    int n = blockIdx.x * 256 + threadIdx.x;
    if (n < N_E) {
        int c = counts[n];
        out_age[n] = (c > 0) ? 0.0f : code_age[n] + 1.0f;
        out_usage[n] = code_usage[n] + (float)c;
    }
    if (n == 0) {
        double mean = *accum / (double)((long)M_TOT * D_DIM);
        out_losses[0] = (float)(0.25 * mean);
        out_losses[1] = (float)mean;
    }
}

extern "C" void kernel_launch(void* const* d_in, const int* in_sizes, int n_in,
                              void* d_out, int out_size, void* d_ws, size_t ws_size,
                              hipStream_t stream) {
    const float* z          = (const float*)d_in[0];
    const float* emb        = (const float*)d_in[1];
    const float* code_age   = (const float*)d_in[2];
    const float* code_usage = (const float*)d_in[3];

    float* out        = (float*)d_out;
    float* out_zq     = out;                       // 8388608
    float* out_losses = out + 8388608;             // 2
    float* out_idx    = out + 8388610;             // 32768
    float* out_age    = out + 8388610 + M_TOT;     // 8192
    float* out_usage  = out_age + N_E;             // 8192

    char* ws = (char*)d_ws;
    _Float16* z_h   = (_Float16*)(ws);             // 16 MB
    _Float16* emb_h = (_Float16*)(ws + 16777216);  // 4 MB
    int* idx_int    = (int*)(ws + 20971520);       // 128 KB
    int* counts     = (int*)(ws + 21102592);       // 32 KB
    int* amb_list   = (int*)(ws + 21135360);       // 128 KB
    int* amb_cnt    = (int*)(ws + 21266432);       // 8
    double* accum   = (double*)(ws + 21266440);    // 8
    u64* bg         = (u64*)(ws + 21266448);       // 256 KB
    float* smax     = (float*)(ws + 21528592);     // 128 KB
    u32* cand       = (u32*)(ws + 21659664);       // 256 KB
    int* cand_cnt   = (int*)(ws + 21921808);       // 4

    k_init<<<128, 256, 0, stream>>>(counts, amb_cnt, accum, bg, cand_cnt);
    k_prep_emb<<<2048, 256, 0, stream>>>(emb, emb_h);
    k_prep_z<<<8192, 256, 0, stream>>>(z, z_h);
    k_argmax<<<M_TOT / BM, 256, 0, stream>>>(z_h, emb_h, out_idx, idx_int,
                                             amb_list, amb_cnt, smax);
    k_cand<<<512, 256, 0, stream>>>(z_h, emb_h, smax, amb_list, amb_cnt,
                                    cand, cand_cnt);
    k_exact<<<256, 256, 0, stream>>>(z, emb, cand, cand_cnt, bg);
    k_emu_write<<<32, 256, 0, stream>>>(amb_list, amb_cnt, bg, out_idx, idx_int);
    k_out<<<8192, 256, 0, stream>>>(z, emb, idx_int, out_zq, accum, counts);
    k_final<<<32, 256, 0, stream>>>(code_age, code_usage, counts, accum,
                                    out_losses, out_age, out_usage);
}